// Round 1
// baseline (260.348 us; speedup 1.0000x reference)
//
#include <hip/hip_runtime.h>

#define BATCH 16
#define NX 1024
#define NY 1024

__global__ __launch_bounds__(256) void fp2d_kernel(
    const float* __restrict__ f,
    const float* __restrict__ Ag,
    const float* __restrict__ Bg,
    const float* __restrict__ dt,
    float* __restrict__ out)
{
    const int y = blockIdx.x * blockDim.x + threadIdx.x;
    const int x = blockIdx.y;
    const int b = blockIdx.z;
    if (y >= NY) return;

    const size_t plane = (size_t)NX * NY;
    const float* __restrict__ fb = f + (size_t)b * plane;
    const float* __restrict__ A0 = Ag;
    const float* __restrict__ A1 = Ag + plane;
    const float* __restrict__ B0 = Bg;
    const float* __restrict__ B1 = Bg + plane;
    const float* __restrict__ B2 = Bg + 2 * plane;

    auto F  = [&](int xx, int yy) { return fb[xx * NY + yy]; };
    auto P  = [&](int xx, int yy) { return A0[xx * NY + yy] * F(xx, yy); }; // A0*f
    auto Q  = [&](int xx, int yy) { return A1[xx * NY + yy] * F(xx, yy); }; // A1*f
    auto R  = [&](int xx)         { return B0[xx * NY + y]  * F(xx, y);  }; // B0*f along x
    auto S  = [&](int yy)         { return B1[x * NY + yy]  * F(x, yy);  }; // B1*f along y
    auto T  = [&](int xx, int yy) { return B2[xx * NY + yy] * F(xx, yy); }; // B2*f

    // ---- d/dx (A0 f), edge_order=2 ----
    float dxP;
    if (x == 0)
        dxP = 0.5f * (-3.0f * P(0, y) + 4.0f * P(1, y) - P(2, y));
    else if (x == NX - 1)
        dxP = 0.5f * ( 3.0f * P(NX - 1, y) - 4.0f * P(NX - 2, y) + P(NX - 3, y));
    else
        dxP = 0.5f * (P(x + 1, y) - P(x - 1, y));

    // ---- d/dy (A1 f) ----
    float dyQ;
    if (y == 0)
        dyQ = 0.5f * (-3.0f * Q(x, 0) + 4.0f * Q(x, 1) - Q(x, 2));
    else if (y == NY - 1)
        dyQ = 0.5f * ( 3.0f * Q(x, NY - 1) - 4.0f * Q(x, NY - 2) + Q(x, NY - 3));
    else
        dyQ = 0.5f * (Q(x, y + 1) - Q(x, y - 1));

    // ---- d2/dx2 (B0 f) ----
    float dxxR;
    if (x == 0)
        dxxR = 2.0f * R(0) - 5.0f * R(1) + 4.0f * R(2) - R(3);
    else if (x == NX - 1)
        dxxR = 2.0f * R(NX - 1) - 5.0f * R(NX - 2) + 4.0f * R(NX - 3) - R(NX - 4);
    else
        dxxR = R(x + 1) - 2.0f * R(x) + R(x - 1);

    // ---- d2/dy2 (B1 f) ----
    float dyyS;
    if (y == 0)
        dyyS = 2.0f * S(0) - 5.0f * S(1) + 4.0f * S(2) - S(3);
    else if (y == NY - 1)
        dyyS = 2.0f * S(NY - 1) - 5.0f * S(NY - 2) + 4.0f * S(NY - 3) - S(NY - 4);
    else
        dyyS = S(y + 1) - 2.0f * S(y) + S(y - 1);

    // ---- mixed: Dx(Dy(B2 f)); DyDx == DxDy (1D ops on different axes commute) ----
    auto dyT = [&](int xx) -> float {
        if (y == 0)
            return 0.5f * (-3.0f * T(xx, 0) + 4.0f * T(xx, 1) - T(xx, 2));
        else if (y == NY - 1)
            return 0.5f * ( 3.0f * T(xx, NY - 1) - 4.0f * T(xx, NY - 2) + T(xx, NY - 3));
        else
            return 0.5f * (T(xx, y + 1) - T(xx, y - 1));
    };
    float dxdyT;
    if (x == 0)
        dxdyT = 0.5f * (-3.0f * dyT(0) + 4.0f * dyT(1) - dyT(2));
    else if (x == NX - 1)
        dxdyT = 0.5f * ( 3.0f * dyT(NX - 1) - 4.0f * dyT(NX - 2) + dyT(NX - 3));
    else
        dxdyT = 0.5f * (dyT(x + 1) - dyT(x - 1));

    const float gradv_Af  = dxP + dyQ;
    const float gradvv_Bf = dxxR + dyyS + 2.0f * dxdyT;
    const float df = -gradv_Af + 0.5f * gradvv_Bf;

    const float val = F(x, y) + df * dt[b];
    out[(size_t)b * plane + (size_t)(x * NY + y)] = fmaxf(val, 0.0f);
}

extern "C" void kernel_launch(void* const* d_in, const int* in_sizes, int n_in,
                              void* d_out, int out_size, void* d_ws, size_t ws_size,
                              hipStream_t stream) {
    const float* f  = (const float*)d_in[0];
    const float* Ag = (const float*)d_in[1];
    const float* Bg = (const float*)d_in[2];
    const float* dt = (const float*)d_in[3];
    float* out = (float*)d_out;

    dim3 block(256, 1, 1);
    dim3 grid(NY / 256, NX, BATCH);
    fp2d_kernel<<<grid, block, 0, stream>>>(f, Ag, Bg, dt, out);
}

// Round 2
// 189.088 us; speedup vs baseline: 1.3769x; 1.3769x over previous
//
#include <hip/hip_runtime.h>

#define BATCH 16
#define NX 1024
#define NY 1024
#define CHUNK 32
#define PLANE (NX * NY)

// Per-row derived quantities carried in the x-march sliding window:
//   fc  = f(x,y)
//   pa  = A0(x,y)*f          (for dxP)
//   rr  = B0(x,y)*f          (for dxxR)
//   dq  = Dy(A1*f) at (x,y)  (dyQ, only needed at center row)
//   d2s = Dyy(B1*f) at (x,y) (dyyS, center row)
//   dtT = Dy(B2*f) at (x,y)  (for the mixed Dx(Dy(B2*f)) term)
struct Row { float fc, pa, rr, dq, d2s, dtT; };

__device__ __forceinline__ Row make_row(int xx, int y,
    const float* __restrict__ fb, const float* __restrict__ A0,
    const float* __restrict__ A1, const float* __restrict__ B0,
    const float* __restrict__ B1, const float* __restrict__ B2)
{
    const int base = xx * NY;
    Row r;
    const float fc = fb[base + y];
    r.fc = fc;
    r.pa = A0[base + y] * fc;
    r.rr = B0[base + y] * fc;
    if (y > 0 && y < NY - 1) {
        const float fm = fb[base + y - 1];
        const float fp = fb[base + y + 1];
        r.dq  = 0.5f * (A1[base + y + 1] * fp - A1[base + y - 1] * fm);
        r.d2s = B1[base + y + 1] * fp - 2.0f * (B1[base + y] * fc)
              + B1[base + y - 1] * fm;
        r.dtT = 0.5f * (B2[base + y + 1] * fp - B2[base + y - 1] * fm);
    } else if (y == 0) {
        const float f1 = fb[base + 1], f2 = fb[base + 2], f3 = fb[base + 3];
        r.dq  = 0.5f * (-3.0f * (A1[base] * fc) + 4.0f * (A1[base + 1] * f1)
                        - A1[base + 2] * f2);
        r.d2s = 2.0f * (B1[base] * fc) - 5.0f * (B1[base + 1] * f1)
              + 4.0f * (B1[base + 2] * f2) - B1[base + 3] * f3;
        r.dtT = 0.5f * (-3.0f * (B2[base] * fc) + 4.0f * (B2[base + 1] * f1)
                        - B2[base + 2] * f2);
    } else { // y == NY-1
        const float f1 = fb[base + NY - 2], f2 = fb[base + NY - 3], f3 = fb[base + NY - 4];
        r.dq  = 0.5f * (3.0f * (A1[base + NY - 1] * fc) - 4.0f * (A1[base + NY - 2] * f1)
                        + A1[base + NY - 3] * f2);
        r.d2s = 2.0f * (B1[base + NY - 1] * fc) - 5.0f * (B1[base + NY - 2] * f1)
              + 4.0f * (B1[base + NY - 3] * f2) - B1[base + NY - 4] * f3;
        r.dtT = 0.5f * (3.0f * (B2[base + NY - 1] * fc) - 4.0f * (B2[base + NY - 2] * f1)
                        + B2[base + NY - 3] * f2);
    }
    return r;
}

__global__ __launch_bounds__(256) void fp2d_kernel(
    const float* __restrict__ f,
    const float* __restrict__ Ag,
    const float* __restrict__ Bg,
    const float* __restrict__ dt,
    float* __restrict__ out)
{
    const int y  = blockIdx.x * 256 + threadIdx.x;
    const int x0 = blockIdx.y * CHUNK;
    const int b  = blockIdx.z;

    const float* __restrict__ fb = f + (size_t)b * PLANE;
    float* __restrict__ ob = out + (size_t)b * PLANE;
    const float dtb = dt[b];
    const float* __restrict__ A0 = Ag;
    const float* __restrict__ A1 = Ag + PLANE;
    const float* __restrict__ B0 = Bg;
    const float* __restrict__ B1 = Bg + PLANE;
    const float* __restrict__ B2 = Bg + 2 * PLANE;

    // Interior centers covered by the sliding-window pipeline.
    int cs = x0;
    int ce = x0 + CHUNK - 1;
    if (cs == 0) cs = 1;                 // x=0 handled one-sided below
    if (ce == NX - 1) ce = NX - 2;       // x=NX-1 handled one-sided below

    Row m = make_row(cs - 1, y, fb, A0, A1, B0, B1, B2);
    Row c = make_row(cs,     y, fb, A0, A1, B0, B1, B2);
    #pragma unroll 4
    for (int x = cs; x <= ce; ++x) {
        Row p = make_row(x + 1, y, fb, A0, A1, B0, B1, B2);
        const float dxP   = 0.5f * (p.pa - m.pa);
        const float dxxR  = p.rr - 2.0f * c.rr + m.rr;
        const float dxdyT = 0.5f * (p.dtT - m.dtT);
        const float df = -(dxP + c.dq) + 0.5f * (dxxR + c.d2s) + dxdyT;
        ob[x * NY + y] = fmaxf(c.fc + df * dtb, 0.0f);
        m = c; c = p;
    }

    // x = 0 one-sided (block-uniform branch: only first chunk)
    if (x0 == 0) {
        Row r0 = make_row(0, y, fb, A0, A1, B0, B1, B2);
        Row r1 = make_row(1, y, fb, A0, A1, B0, B1, B2);
        Row r2 = make_row(2, y, fb, A0, A1, B0, B1, B2);
        Row r3 = make_row(3, y, fb, A0, A1, B0, B1, B2);
        const float dxP   = 0.5f * (-3.0f * r0.pa + 4.0f * r1.pa - r2.pa);
        const float dxxR  = 2.0f * r0.rr - 5.0f * r1.rr + 4.0f * r2.rr - r3.rr;
        const float dxdyT = 0.5f * (-3.0f * r0.dtT + 4.0f * r1.dtT - r2.dtT);
        const float df = -(dxP + r0.dq) + 0.5f * (dxxR + r0.d2s) + dxdyT;
        ob[y] = fmaxf(r0.fc + df * dtb, 0.0f);
    }

    // x = NX-1 one-sided (only last chunk)
    if (x0 + CHUNK == NX) {
        Row r0 = make_row(NX - 1, y, fb, A0, A1, B0, B1, B2);
        Row r1 = make_row(NX - 2, y, fb, A0, A1, B0, B1, B2);
        Row r2 = make_row(NX - 3, y, fb, A0, A1, B0, B1, B2);
        Row r3 = make_row(NX - 4, y, fb, A0, A1, B0, B1, B2);
        const float dxP   = 0.5f * (3.0f * r0.pa - 4.0f * r1.pa + r2.pa);
        const float dxxR  = 2.0f * r0.rr - 5.0f * r1.rr + 4.0f * r2.rr - r3.rr;
        const float dxdyT = 0.5f * (3.0f * r0.dtT - 4.0f * r1.dtT + r2.dtT);
        const float df = -(dxP + r0.dq) + 0.5f * (dxxR + r0.d2s) + dxdyT;
        ob[(NX - 1) * NY + y] = fmaxf(r0.fc + df * dtb, 0.0f);
    }
}

extern "C" void kernel_launch(void* const* d_in, const int* in_sizes, int n_in,
                              void* d_out, int out_size, void* d_ws, size_t ws_size,
                              hipStream_t stream) {
    const float* f  = (const float*)d_in[0];
    const float* Ag = (const float*)d_in[1];
    const float* Bg = (const float*)d_in[2];
    const float* dt = (const float*)d_in[3];
    float* out = (float*)d_out;

    dim3 block(256, 1, 1);
    dim3 grid(NY / 256, NX / CHUNK, BATCH);
    fp2d_kernel<<<grid, block, 0, stream>>>(f, Ag, Bg, dt, out);
}

// Round 3
// 170.297 us; speedup vs baseline: 1.5288x; 1.1103x over previous
//
#include <hip/hip_runtime.h>

#define BATCH 16
#define NX 1024
#define NY 1024
#define CHUNK 16
#define PLANE (NX * NY)

// Each thread owns 4 consecutive y values (y0..y0+3); a 256-thread block
// covers the full y-extent of one row. Threads march x across a CHUNK,
// carrying per-row derived quantities in registers (sliding window m/c/p).
struct Row4 {
    float fc[4];   // f
    float pa[4];   // A0*f
    float rr[4];   // B0*f
    float dq[4];   // Dy(A1*f)
    float d2s[4];  // Dyy(B1*f)
    float dtT[4];  // Dy(B2*f)
};

__device__ __forceinline__ Row4 make_row4(
    int xx, int y0, int tid,
    const float* __restrict__ fb, const float* __restrict__ A0,
    const float* __restrict__ A1, const float* __restrict__ B0,
    const float* __restrict__ B1, const float* __restrict__ B2)
{
    const int base = xx * NY + y0;
    const bool has_l = (tid > 0);
    const bool has_r = (tid < 255);

    // f: center float4 + halo scalars
    const float4 f4 = *(const float4*)(fb + base);
    const float fl = has_l ? fb[base - 1] : 0.0f;
    const float fr = has_r ? fb[base + 4] : 0.0f;

    const float4 a0 = *(const float4*)(A0 + base);
    const float4 b0 = *(const float4*)(B0 + base);

    const float4 a1 = *(const float4*)(A1 + base);
    const float a1l = has_l ? A1[base - 1] : 0.0f;
    const float a1r = has_r ? A1[base + 4] : 0.0f;

    const float4 b1 = *(const float4*)(B1 + base);
    const float b1l = has_l ? B1[base - 1] : 0.0f;
    const float b1r = has_r ? B1[base + 4] : 0.0f;

    const float4 b2 = *(const float4*)(B2 + base);
    const float b2l = has_l ? B2[base - 1] : 0.0f;
    const float b2r = has_r ? B2[base + 4] : 0.0f;

    // extended products over y0-1 .. y0+4
    float fe[6] = { fl, f4.x, f4.y, f4.z, f4.w, fr };
    float qe[6] = { a1l * fl, a1.x * f4.x, a1.y * f4.y, a1.z * f4.z, a1.w * f4.w, a1r * fr };
    float se[6] = { b1l * fl, b1.x * f4.x, b1.y * f4.y, b1.z * f4.z, b1.w * f4.w, b1r * fr };
    float te[6] = { b2l * fl, b2.x * f4.x, b2.y * f4.y, b2.z * f4.z, b2.w * f4.w, b2r * fr };

    Row4 r;
    r.fc[0] = fe[1]; r.fc[1] = fe[2]; r.fc[2] = fe[3]; r.fc[3] = fe[4];
    r.pa[0] = a0.x * f4.x; r.pa[1] = a0.y * f4.y; r.pa[2] = a0.z * f4.z; r.pa[3] = a0.w * f4.w;
    r.rr[0] = b0.x * f4.x; r.rr[1] = b0.y * f4.y; r.rr[2] = b0.z * f4.z; r.rr[3] = b0.w * f4.w;

    #pragma unroll
    for (int i = 0; i < 4; ++i) {
        r.dq[i]  = 0.5f * (qe[i + 2] - qe[i]);
        r.d2s[i] = se[i + 2] - 2.0f * se[i + 1] + se[i];
        r.dtT[i] = 0.5f * (te[i + 2] - te[i]);
    }
    // y = 0 one-sided (element 0 of tid 0)
    if (tid == 0) {
        r.dq[0]  = 0.5f * (-3.0f * qe[1] + 4.0f * qe[2] - qe[3]);
        r.d2s[0] = 2.0f * se[1] - 5.0f * se[2] + 4.0f * se[3] - se[4];
        r.dtT[0] = 0.5f * (-3.0f * te[1] + 4.0f * te[2] - te[3]);
    }
    // y = NY-1 one-sided (element 3 of tid 255)
    if (tid == 255) {
        r.dq[3]  = 0.5f * (3.0f * qe[4] - 4.0f * qe[3] + qe[2]);
        r.d2s[3] = 2.0f * se[4] - 5.0f * se[3] + 4.0f * se[2] - se[1];
        r.dtT[3] = 0.5f * (3.0f * te[4] - 4.0f * te[3] + te[2]);
    }
    return r;
}

__global__ __launch_bounds__(256) void fp2d_kernel(
    const float* __restrict__ f,
    const float* __restrict__ Ag,
    const float* __restrict__ Bg,
    const float* __restrict__ dt,
    float* __restrict__ out)
{
    const int tid = threadIdx.x;
    const int y0  = tid * 4;
    const int x0  = blockIdx.x * CHUNK;   // xc fastest -> XCD gets xc = k mod 8 (L2 grid reuse)
    const int b   = blockIdx.y;

    const float* __restrict__ fb = f + (size_t)b * PLANE;
    float* __restrict__ ob = out + (size_t)b * PLANE;
    const float dtb = dt[b];
    const float* __restrict__ A0 = Ag;
    const float* __restrict__ A1 = Ag + PLANE;
    const float* __restrict__ B0 = Bg;
    const float* __restrict__ B1 = Bg + PLANE;
    const float* __restrict__ B2 = Bg + 2 * PLANE;

    int cs = x0;
    int ce = x0 + CHUNK - 1;
    if (cs == 0) cs = 1;
    if (ce == NX - 1) ce = NX - 2;

    Row4 m = make_row4(cs - 1, y0, tid, fb, A0, A1, B0, B1, B2);
    Row4 c = make_row4(cs,     y0, tid, fb, A0, A1, B0, B1, B2);
    #pragma unroll 2
    for (int x = cs; x <= ce; ++x) {
        Row4 p = make_row4(x + 1, y0, tid, fb, A0, A1, B0, B1, B2);
        float4 o;
        float* op = &o.x;
        #pragma unroll
        for (int i = 0; i < 4; ++i) {
            const float dxP   = 0.5f * (p.pa[i] - m.pa[i]);
            const float dxxR  = p.rr[i] - 2.0f * c.rr[i] + m.rr[i];
            const float dxdyT = 0.5f * (p.dtT[i] - m.dtT[i]);
            const float df = -(dxP + c.dq[i]) + 0.5f * (dxxR + c.d2s[i]) + dxdyT;
            op[i] = fmaxf(c.fc[i] + df * dtb, 0.0f);
        }
        *(float4*)(ob + x * NY + y0) = o;
        m = c; c = p;
    }

    // x = 0 one-sided (only first chunk; block-uniform branch)
    if (x0 == 0) {
        Row4 r0 = make_row4(0, y0, tid, fb, A0, A1, B0, B1, B2);
        Row4 r1 = make_row4(1, y0, tid, fb, A0, A1, B0, B1, B2);
        Row4 r2 = make_row4(2, y0, tid, fb, A0, A1, B0, B1, B2);
        Row4 r3 = make_row4(3, y0, tid, fb, A0, A1, B0, B1, B2);
        float4 o; float* op = &o.x;
        #pragma unroll
        for (int i = 0; i < 4; ++i) {
            const float dxP   = 0.5f * (-3.0f * r0.pa[i] + 4.0f * r1.pa[i] - r2.pa[i]);
            const float dxxR  = 2.0f * r0.rr[i] - 5.0f * r1.rr[i] + 4.0f * r2.rr[i] - r3.rr[i];
            const float dxdyT = 0.5f * (-3.0f * r0.dtT[i] + 4.0f * r1.dtT[i] - r2.dtT[i]);
            const float df = -(dxP + r0.dq[i]) + 0.5f * (dxxR + r0.d2s[i]) + dxdyT;
            op[i] = fmaxf(r0.fc[i] + df * dtb, 0.0f);
        }
        *(float4*)(ob + y0) = o;
    }

    // x = NX-1 one-sided (only last chunk)
    if (x0 + CHUNK == NX) {
        Row4 r0 = make_row4(NX - 1, y0, tid, fb, A0, A1, B0, B1, B2);
        Row4 r1 = make_row4(NX - 2, y0, tid, fb, A0, A1, B0, B1, B2);
        Row4 r2 = make_row4(NX - 3, y0, tid, fb, A0, A1, B0, B1, B2);
        Row4 r3 = make_row4(NX - 4, y0, tid, fb, A0, A1, B0, B1, B2);
        float4 o; float* op = &o.x;
        #pragma unroll
        for (int i = 0; i < 4; ++i) {
            const float dxP   = 0.5f * (3.0f * r0.pa[i] - 4.0f * r1.pa[i] + r2.pa[i]);
            const float dxxR  = 2.0f * r0.rr[i] - 5.0f * r1.rr[i] + 4.0f * r2.rr[i] - r3.rr[i];
            const float dxdyT = 0.5f * (3.0f * r0.dtT[i] - 4.0f * r1.dtT[i] + r2.dtT[i]);
            const float df = -(dxP + r0.dq[i]) + 0.5f * (dxxR + r0.d2s[i]) + dxdyT;
            op[i] = fmaxf(r0.fc[i] + df * dtb, 0.0f);
        }
        *(float4*)(ob + (NX - 1) * NY + y0) = o;
    }
}

extern "C" void kernel_launch(void* const* d_in, const int* in_sizes, int n_in,
                              void* d_out, int out_size, void* d_ws, size_t ws_size,
                              hipStream_t stream) {
    const float* f  = (const float*)d_in[0];
    const float* Ag = (const float*)d_in[1];
    const float* Bg = (const float*)d_in[2];
    const float* dt = (const float*)d_in[3];
    float* out = (float*)d_out;

    dim3 block(256, 1, 1);
    dim3 grid(NX / CHUNK, BATCH, 1);
    fp2d_kernel<<<grid, block, 0, stream>>>(f, Ag, Bg, dt, out);
}